// Round 7
// baseline (239.740 us; speedup 1.0000x reference)
//
#include <hip/hip_runtime.h>

#define LSZ   16
#define NBATCH 2
#define NSITE (NBATCH*LSZ*LSZ*LSZ*LSZ)   // 131072
#define NIN   10
#define NOUT  8
#define ND    4
#define NCPLX ((long)NSITE * NOUT * 9)   // 9,437,184 complex output elements
#define NLINE_PER_DIR (NSITE / LSZ)      // 8192
#define NLINK (NSITE * ND)               // 524288
#define WSTRIDE 108                      // u32 per site in LDS image: 9 e * 12 ch (10 used)

typedef unsigned int u32;
typedef float  f32x4 __attribute__((ext_vector_type(4)));
typedef short  s16x8 __attribute__((ext_vector_type(8)));

struct M3 { float re[9]; float im[9]; };

// bf16 pack helpers: u32 = bf16(lo) | bf16(hi)<<16
__device__ __forceinline__ unsigned short f2bf(float x) {
    u32 u = __float_as_uint(x);
    u32 r = (u + 0x7fffu + ((u >> 16) & 1u)) >> 16;   // RNE
    return (unsigned short)r;
}
__device__ __forceinline__ u32 packbf(float lo, float hi) {
    return (u32)f2bf(lo) | ((u32)f2bf(hi) << 16);
}

__device__ __forceinline__ s16x8 as_s16x8(uint4 v) {
    union { uint4 u; s16x8 s; } x; x.u = v; return x.s;
}

// o = a * b
__device__ __forceinline__ void mulM(M3& o, const M3& a, const M3& b) {
#pragma unroll
    for (int r = 0; r < 3; r++) {
#pragma unroll
        for (int c = 0; c < 3; c++) {
            float xr = 0.f, xi = 0.f;
#pragma unroll
            for (int k = 0; k < 3; k++) {
                float ar = a.re[r*3+k], ai = a.im[r*3+k];
                float br = b.re[k*3+c], bi = b.im[k*3+c];
                xr = fmaf(ar, br, xr); xr = fmaf(-ai, bi, xr);
                xi = fmaf(ar, bi, xi); xi = fmaf(ai, br, xi);
            }
            o.re[r*3+c] = xr; o.im[r*3+c] = xi;
        }
    }
}

// o = a * b^H
__device__ __forceinline__ void mulAdjM(M3& o, const M3& a, const M3& b) {
#pragma unroll
    for (int r = 0; r < 3; r++) {
#pragma unroll
        for (int c = 0; c < 3; c++) {
            float xr = 0.f, xi = 0.f;
#pragma unroll
            for (int k = 0; k < 3; k++) {
                float ar = a.re[r*3+k], ai = a.im[r*3+k];
                float br = b.re[c*3+k], bi = b.im[c*3+k];
                xr = fmaf(ar, br, xr); xr = fmaf(ai, bi, xr);
                xi = fmaf(ai, br, xi); xi = fmaf(-ar, bi, xi);
            }
            o.re[r*3+c] = xr; o.im[r*3+c] = xi;
        }
    }
}

// site s = b*65536 + x*4096 + y*256 + z*16 + t ; mu: 0->x,1->y,2->z,3->t
__device__ __forceinline__ int shift_site(int s, int mu, int k) {
    int sh = 12 - 4 * mu;
    int c  = (s >> sh) & 15;
    int nc = (c + k) & 15;
    return (s & ~(15 << sh)) | (nc << sh);
}

// ---------------- Kernel 1: Polyakov -> site-major T2 ------------------------
// Coalesced LDS staging + parallel doubling scan (4 matmuls/thread via
// intra-wave __shfl). Direct per-lane loads (round 5) were scattered at
// (1<<sh)*144B lane stride -> L1-line (TA) pathology.
__global__ __launch_bounds__(256) void poly_kernel(const float* __restrict__ Ure,
                                                   const float* __restrict__ Uim,
                                                   u32* __restrict__ T2) {
    __shared__ float2 sm[16 * 145];   // 18.56 KB

    int line0 = blockIdx.x * 16;
    int mu    = line0 / NLINE_PER_DIR;
    int lidx0 = line0 - mu * NLINE_PER_DIR;
    int sh    = 12 - 4 * mu;
    int low0  = lidx0 & ((1 << sh) - 1);
    int high0 = lidx0 >> sh;
    int s_base0 = (high0 << (sh + 4)) | low0;

    for (int n = threadIdx.x; n < 16 * 16 * 9; n += 256) {
        int siteIdx = n / 9;
        int e       = n - siteIdx * 9;
        int site, l, c;
        if (mu == 3) { site = (lidx0 << 4) + siteIdx; l = siteIdx >> 4; c = siteIdx & 15; }
        else         { site = s_base0 + ((siteIdx >> 4) << sh) + (siteIdx & 15);
                       l = siteIdx & 15; c = siteIdx >> 4; }
        long g = ((long)site * 4 + mu) * 9 + e;
        sm[l * 145 + c * 9 + e] = make_float2(Ure[g], Uim[g]);
    }
    __syncthreads();

    int lane = threadIdx.x & 63;
    int c    = threadIdx.x & 15;
    int l    = threadIdx.x >> 4;

    M3 P;
    {
        const float2* m0 = &sm[l * 145 + c * 9];
#pragma unroll
        for (int e = 0; e < 9; e++) { float2 v = m0[e]; P.re[e] = v.x; P.im[e] = v.y; }
    }

    // doubling scan: M2(c)=U_c*U_{c+1}; M4=M2*M2(+2); M8; M16 = P_c (mod 16).
#pragma unroll
    for (int k = 1; k < 16; k <<= 1) {
        int src = (lane & 48) | ((c + k) & 15);
        M3 Q, T;
#pragma unroll
        for (int e = 0; e < 9; e++) {
            Q.re[e] = __shfl(P.re[e], src);
            Q.im[e] = __shfl(P.im[e], src);
        }
        mulM(T, P, Q);
        P = T;
    }

    int lidx = lidx0 + l;
    int low  = lidx & ((1 << sh) - 1);
    int high = lidx >> sh;
    int site = (high << (sh + 4)) | (c << sh) | low;
    u32* Tp = T2 + ((long)site * 4 + mu) * 9;
#pragma unroll
    for (int e = 0; e < 9; e++) Tp[e] = packbf(P.re[e], P.im[e]);
}

// ------- Kernel 2: plaquettes + merge-poly -> W planes -----------------------
// Staged version (round-5): sU cooperative coalesced staging (consecutive
// threads -> consecutive addresses, ~8 lines/instr vs ~40-64 for the direct
// per-lane loads of round 6 -- L1-line throughput is the binding resource).
// LDS: sU (37.9 KB) unioned with sw (13.8 KB, time-disjoint). T2 gather
// prefetched to registers at kernel top (coalesced), written after barrier.
__global__ __launch_bounds__(192) void plaq_merge_kernel(const float* __restrict__ Ure,
                                                         const float* __restrict__ Uim,
                                                         const u32* __restrict__ T2,
                                                         u32* __restrict__ W) {
    __shared__ __align__(16) char smem[4 * 32 * 37 * sizeof(float2)];   // 37,888 B
    float2* sU = (float2*)smem;      // live: stage .. P compute
    u32*    sw = (u32*)smem;         // live: after barrier .. W4 write (13,824 B)

    int s0 = blockIdx.x * 32;

    // early T2 prefetch: coalesced s0*36 + it
    u32 tpre[6]; int tofs[6];
#pragma unroll
    for (int w = 0; w < 6; w++) {
        int it = threadIdx.x + w * 192;
        tpre[w] = T2[(long)s0 * 36 + it];
        int ls2 = it / 36;
        int r   = it - ls2 * 36;
        int mu2 = r / 9;
        int e2  = r - mu2 * 9;
        tofs[w] = ls2 * WSTRIDE + e2 * 12 + 6 + mu2;
    }

    for (int n = threadIdx.x; n < 8 * 16 * 36; n += 192) {
        int run = n / 576;
        int q   = n - run * 576;
        int sir = q / 36;
        int e36 = q - sir * 36;
        int slot = run >> 1, r = run & 1;
        int base = s0 + r * 16;
        if (slot < 3) base = shift_site(base, slot, 1);
        long g = (long)(base + sir) * 36 + e36;
        sU[(slot * 32 + r * 16 + sir) * 37 + e36] = make_float2(Ure[g], Uim[g]);
    }
    __syncthreads();

    int p  = threadIdx.x >> 5;
    int ls = threadIdx.x & 31;

    int mu = (p < 3) ? 0 : ((p < 5) ? 1 : 2);
    int nu = (mu == 0) ? (p + 1) : ((mu == 1) ? (p - 1) : 3);

    M3 Umu, Unu, Unu_f, Umu_f, T1, T2m, P;
    {
        const float2* pp;
#define LDM(m, slot, site, link) \
        pp = &sU[((slot) * 32 + (site)) * 37 + (link) * 9]; \
        _Pragma("unroll") \
        for (int e = 0; e < 9; e++) { float2 v = pp[e]; (m).re[e] = v.x; (m).im[e] = v.y; }

        LDM(Umu, 3, ls, mu);
        LDM(Unu, 3, ls, nu);
        LDM(Unu_f, mu, ls, nu);
        int lsrot = (ls & 16) | ((ls + 1) & 15);
        int fslot = (nu == 3) ? 3 : nu;
        int fsite = (nu == 3) ? lsrot : ls;
        LDM(Umu_f, fslot, fsite, mu);
#undef LDM
    }

    mulM(T1, Umu, Unu_f);
    mulAdjM(T2m, T1, Umu_f);
    mulAdjM(P, T2m, Unu);

    __syncthreads();   // all sU reads done; reuse LDS as sw

#pragma unroll
    for (int e = 0; e < 9; e++) sw[ls * WSTRIDE + e * 12 + p] = packbf(P.re[e], P.im[e]);

    // pad j-slots 10,11 zeroed
    for (int it = threadIdx.x; it < 32 * 9 * 2; it += 192) {
        int site = it / 18;
        int r    = it - site * 18;
        sw[site * WSTRIDE + (r >> 1) * 12 + 10 + (r & 1)] = 0u;
    }

    // T2 merge (j-slots 6..9)
#pragma unroll
    for (int w = 0; w < 6; w++) sw[tofs[w]] = tpre[w];
    __syncthreads();

    // plane-transposed write: 27 planes x 32 consecutive uint4
    uint4* W4 = (uint4*)W;
    for (int it = threadIdx.x; it < 27 * 32; it += 192) {
        int pl  = it >> 5;
        int ls2 = it & 31;
        int e   = pl / 3, q = pl - e * 3;
        const uint4 v = *(const uint4*)(sw + ls2 * WSTRIDE + e * 12 + q * 4);
        W4[(long)pl * NSITE + s0 + ls2] = v;
    }
}

// ---------------- Kernel 3: MFMA gauge-equivariant conv ----------------------
// One wave per 16-site t-line. mfma_f32_16x16x32_bf16 per (mu,kk,e).
// Round-7 change: U links staged coalesced into LDS at block top (64 sites x
// 4 mu x 9 cplx = 18.4 KB); epilogue A-reads become broadcast LDS reads.
// Previously 144 global dword loads/thread at 144B lane stride (~12 L1
// lines/instr after 8-way dedup) -- L1-line-throughput bound.
// LDS: somB 12.3 KB + union(sU 18.4 KB | sout 18.4 KB) = 30.7 KB.
// NOTE: never cap VGPRs via launch_bounds min-waves (round 1: 17x slower).
template <int MODE>
__global__ __launch_bounds__(256) void conv_kernel(const float* __restrict__ Ure,
                                                   const float* __restrict__ Uim,
                                                   const u32* __restrict__ W,
                                                   const float* __restrict__ omre,
                                                   const float* __restrict__ omim,
                                                   float* __restrict__ out) {
    __shared__ __align__(16) char smraw[12288 + 18432];   // 30,720 B
    uint4*  somB = (uint4*)smraw;             // [mk*64+lane], live during loop
    float2* sU   = (float2*)(smraw + 12288);  // [siteLoc*36 + mu*9 + e], live during loop
    float*  sout = (float*)(smraw + 12288);   // live after loop (MODE 2)

    // B-fragment precompute: lane (c=lane&15, q=lane>>4); word w -> j=q*4+w
    for (int n = threadIdx.x; n < 12 * 64; n += 256) {
        int mk = n >> 6, ln = n & 63;
        int q = ln >> 4, c = ln & 15, i = c & 7;
        int mu = mk / 3, kk = mk - mu * 3;
        u32 wv[4];
#pragma unroll
        for (int w = 0; w < 4; w++) {
            int j = q * 4 + w;
            u32 val = 0u;
            if (q < 3 && j < NIN) {
                int oidx = ((i * NIN + j) * ND + mu) * 3 + kk;
                float orv = omre[oidx], oiv = omim[oidx];
                val = (c < 8) ? packbf(orv, -oiv) : packbf(oiv, orv);
            }
            wv[w] = val;
        }
        somB[n] = make_uint4(wv[0], wv[1], wv[2], wv[3]);
    }

    // XCD-aware bijective swizzle (gridDim.x = 2048, divisible by 8)
    int chunk = gridDim.x >> 3;
    int lb    = ((int)blockIdx.x & 7) * chunk + ((int)blockIdx.x >> 3);
    int s0b   = lb * 64;

    // coalesced U staging: Ure/Uim index (site*4+mu)*9+e == site*36+mu*9+e
    for (int n = threadIdx.x; n < 64 * 36; n += 256) {
        long g = (long)s0b * 36 + n;
        sU[n] = make_float2(Ure[g], Uim[g]);
    }
    __syncthreads();

    int lane = threadIdx.x & 63;
    int wv_  = threadIdx.x >> 6;          // 0..3
    int r    = lane & 15;                 // A-row (t) / D-col (channel-part)
    int q    = lane >> 4;                 // k-quad / D-row block
    int sline = s0b + wv_ * 16;

    const uint4* W4 = (const uint4*)W;

    bool hi = (r >= 8);
    int  i  = r & 7;                      // output channel for epilogue
    int  reg0 = hi ? 2 : 0;               // D-rows handled by this lane

    float accr[2][9], acci[2][9];
#pragma unroll
    for (int rr = 0; rr < 2; rr++)
#pragma unroll
        for (int e = 0; e < 9; e++) { accr[rr][e] = 0.f; acci[rr][e] = 0.f; }

    for (int mu = 0; mu < ND; mu++) {
        f32x4 acc[9];
#pragma unroll
        for (int e = 0; e < 9; e++) acc[e] = (f32x4)(0.f);

        for (int kk = 0; kk < 3; kk++) {
            int mk = mu * 3 + kk;
            s16x8 bfrag = as_s16x8(somB[mk * 64 + lane]);

            int nb;
            if (mu < 3) nb = shift_site(sline, mu, kk - 1) + r;
            else        nb = sline + ((r + kk - 1) & 15);

            uint4 w9[9];
            if (q < 3) {
#pragma unroll
                for (int e = 0; e < 9; e++) w9[e] = W4[(long)(e * 3 + q) * NSITE + nb];
            } else {
#pragma unroll
                for (int e = 0; e < 9; e++) w9[e] = make_uint4(0u, 0u, 0u, 0u);
            }
#pragma unroll
            for (int e = 0; e < 9; e++)
                acc[e] = __builtin_amdgcn_mfma_f32_16x16x32_bf16(as_s16x8(w9[e]), bfrag, acc[e], 0, 0, 0);
        }

        // exchange: partner holds the other complex part of M for my 2 rows
        float own[2][9], oth[2][9];
#pragma unroll
        for (int e = 0; e < 9; e++) {
            float t0 = __shfl_xor(acc[e][0], 8);
            float t1 = __shfl_xor(acc[e][1], 8);
            float t2 = __shfl_xor(acc[e][2], 8);
            float t3 = __shfl_xor(acc[e][3], 8);
            own[0][e] = hi ? acc[e][2] : acc[e][0];
            own[1][e] = hi ? acc[e][3] : acc[e][1];
            oth[0][e] = hi ? t2 : t0;
            oth[1][e] = hi ? t3 : t1;
        }

        // sandwich A * M * A^H for this lane's 2 sites (A from LDS broadcast)
#pragma unroll
        for (int rr = 0; rr < 2; rr++) {
            int siteLoc = wv_ * 16 + q * 4 + reg0 + rr;
            M3 A, M;
            {
                const float2* pA = sU + siteLoc * 36 + mu * 9;
#pragma unroll
                for (int e = 0; e < 9; e++) { float2 v = pA[e]; A.re[e] = v.x; A.im[e] = v.y; }
            }
#pragma unroll
            for (int e = 0; e < 9; e++) {
                M.re[e] = hi ? oth[rr][e] : own[rr][e];
                M.im[e] = hi ? own[rr][e] : oth[rr][e];
            }
            M3 Tm;
#pragma unroll
            for (int rw = 0; rw < 3; rw++) {
#pragma unroll
                for (int cl = 0; cl < 3; cl++) {
                    float xr = 0.f, xi = 0.f;
#pragma unroll
                    for (int k = 0; k < 3; k++) {
                        float ar = A.re[rw*3+k], ai = A.im[rw*3+k];
                        float br = M.re[k*3+cl], bi = M.im[k*3+cl];
                        xr = fmaf(ar, br, xr); xr = fmaf(-ai, bi, xr);
                        xi = fmaf(ar, bi, xi); xi = fmaf(ai, br, xi);
                    }
                    Tm.re[rw*3+cl] = xr; Tm.im[rw*3+cl] = xi;
                }
            }
#pragma unroll
            for (int rw = 0; rw < 3; rw++) {
#pragma unroll
                for (int cl = 0; cl < 3; cl++) {
                    float xr = 0.f, xi = 0.f;
#pragma unroll
                    for (int k = 0; k < 3; k++) {
                        float ar = Tm.re[rw*3+k], ai = Tm.im[rw*3+k];
                        float br = A.re[cl*3+k], bi = A.im[cl*3+k];
                        xr = fmaf(ar, br, xr); xr = fmaf(ai, bi, xr);
                        if (MODE != 2) { xi = fmaf(ai, br, xi); xi = fmaf(-ar, bi, xi); }
                    }
                    accr[rr][rw*3+cl] += xr;
                    if (MODE != 2) acci[rr][rw*3+cl] += xi;
                }
            }
        }
    }

    if (MODE == 2) {
        __syncthreads();   // all somB/sU reads done before aliasing as sout
#pragma unroll
        for (int rr = 0; rr < 2; rr++) {
            int tloc = wv_ * 16 + q * 4 + reg0 + rr;
#pragma unroll
            for (int e = 0; e < 9; e++)
                sout[(tloc * 8 + i) * 9 + e] = accr[rr][e];
        }
        __syncthreads();
        long base = (long)lb * 4608;
        for (int n = threadIdx.x; n < 4608; n += 256) out[base + n] = sout[n];
    } else if (MODE == 0) {
#pragma unroll
        for (int rr = 0; rr < 2; rr++) {
            int site = sline + q * 4 + reg0 + rr;
            long cb = ((long)site * 8 + i) * 9;
            float2* op = (float2*)(out + cb * 2);
#pragma unroll
            for (int e = 0; e < 9; e++) op[e] = make_float2(accr[rr][e], acci[rr][e]);
        }
    } else {
#pragma unroll
        for (int rr = 0; rr < 2; rr++) {
            int site = sline + q * 4 + reg0 + rr;
            long cb = ((long)site * 8 + i) * 9;
#pragma unroll
            for (int e = 0; e < 9; e++) {
                out[cb + e]         = accr[rr][e];
                out[NCPLX + cb + e] = acci[rr][e];
            }
        }
    }
}

extern "C" void kernel_launch(void* const* d_in, const int* in_sizes, int n_in,
                              void* d_out, int out_size, void* d_ws, size_t ws_size,
                              hipStream_t stream) {
    const float* Ure  = (const float*)d_in[0];
    const float* Uim  = (const float*)d_in[1];
    const float* omre = (const float*)d_in[2];
    const float* omim = (const float*)d_in[3];
    float* out = (float*)d_out;

    const size_t wBytes = (size_t)NSITE * WSTRIDE * sizeof(u32);   // 56.6 MB (27 planes)
    if (ws_size < wBytes) return;

    u32* W  = (u32*)d_ws;
    u32* T2 = (u32*)d_out;   // 18.9 MB temp in d_out; overwritten by conv

    poly_kernel<<<NSITE * 4 / (16 * 16), 256, 0, stream>>>(Ure, Uim, T2);
    plaq_merge_kernel<<<NSITE / 32, 192, 0, stream>>>(Ure, Uim, T2, W);

    const int convGrid = NSITE / 64;   // 2048 blocks, 64 sites each (4 waves)
    if (out_size == (int)NCPLX)
        conv_kernel<2><<<convGrid, 256, 0, stream>>>(Ure, Uim, W, omre, omim, out);
    else if (out_size == (int)(2 * NCPLX))
        conv_kernel<1><<<convGrid, 256, 0, stream>>>(Ure, Uim, W, omre, omim, out);
    else
        conv_kernel<0><<<convGrid, 256, 0, stream>>>(Ure, Uim, W, omre, omim, out);
}

// Round 8
// 218.718 us; speedup vs baseline: 1.0961x; 1.0961x over previous
//
#include <hip/hip_runtime.h>

#define LSZ   16
#define NBATCH 2
#define NSITE (NBATCH*LSZ*LSZ*LSZ*LSZ)   // 131072
#define NIN   10
#define NOUT  8
#define ND    4
#define NCPLX ((long)NSITE * NOUT * 9)   // 9,437,184 complex output elements
#define NLINE_PER_DIR (NSITE / LSZ)      // 8192
#define NLINK (NSITE * ND)               // 524288
#define WSTRIDE 108                      // u32 per site in LDS image: 9 e * 12 ch (10 used)

typedef unsigned int u32;
typedef float  f32x4 __attribute__((ext_vector_type(4)));
typedef short  s16x8 __attribute__((ext_vector_type(8)));
// dword-aligned float4: gfx950 global loads support dword-aligned dwordx4;
// aligned(4) keeps it non-UB while still emitting global_load_dwordx4.
typedef float  f32x4a __attribute__((ext_vector_type(4), aligned(4)));

struct M3 { float re[9]; float im[9]; };

// load a 9-float (36B) row with 2x dwordx4 + 1 dword instead of 9 dwords
__device__ __forceinline__ void load9(float d[9], const float* __restrict__ p) {
    f32x4a a = *reinterpret_cast<const f32x4a*>(p);
    f32x4a b = *reinterpret_cast<const f32x4a*>(p + 4);
    d[0] = a[0]; d[1] = a[1]; d[2] = a[2]; d[3] = a[3];
    d[4] = b[0]; d[5] = b[1]; d[6] = b[2]; d[7] = b[3];
    d[8] = p[8];
}

// bf16 pack helpers: u32 = bf16(lo) | bf16(hi)<<16
__device__ __forceinline__ unsigned short f2bf(float x) {
    u32 u = __float_as_uint(x);
    u32 r = (u + 0x7fffu + ((u >> 16) & 1u)) >> 16;   // RNE
    return (unsigned short)r;
}
__device__ __forceinline__ u32 packbf(float lo, float hi) {
    return (u32)f2bf(lo) | ((u32)f2bf(hi) << 16);
}

__device__ __forceinline__ s16x8 as_s16x8(uint4 v) {
    union { uint4 u; s16x8 s; } x; x.u = v; return x.s;
}

// o = a * b
__device__ __forceinline__ void mulM(M3& o, const M3& a, const M3& b) {
#pragma unroll
    for (int r = 0; r < 3; r++) {
#pragma unroll
        for (int c = 0; c < 3; c++) {
            float xr = 0.f, xi = 0.f;
#pragma unroll
            for (int k = 0; k < 3; k++) {
                float ar = a.re[r*3+k], ai = a.im[r*3+k];
                float br = b.re[k*3+c], bi = b.im[k*3+c];
                xr = fmaf(ar, br, xr); xr = fmaf(-ai, bi, xr);
                xi = fmaf(ar, bi, xi); xi = fmaf(ai, br, xi);
            }
            o.re[r*3+c] = xr; o.im[r*3+c] = xi;
        }
    }
}

// o = a * b^H
__device__ __forceinline__ void mulAdjM(M3& o, const M3& a, const M3& b) {
#pragma unroll
    for (int r = 0; r < 3; r++) {
#pragma unroll
        for (int c = 0; c < 3; c++) {
            float xr = 0.f, xi = 0.f;
#pragma unroll
            for (int k = 0; k < 3; k++) {
                float ar = a.re[r*3+k], ai = a.im[r*3+k];
                float br = b.re[c*3+k], bi = b.im[c*3+k];
                xr = fmaf(ar, br, xr); xr = fmaf(ai, bi, xr);
                xi = fmaf(ai, br, xi); xi = fmaf(-ar, bi, xi);
            }
            o.re[r*3+c] = xr; o.im[r*3+c] = xi;
        }
    }
}

// site s = b*65536 + x*4096 + y*256 + z*16 + t ; mu: 0->x,1->y,2->z,3->t
__device__ __forceinline__ int shift_site(int s, int mu, int k) {
    int sh = 12 - 4 * mu;
    int c  = (s >> sh) & 15;
    int nc = (c + k) & 15;
    return (s & ~(15 << sh)) | (nc << sh);
}

// ---------------- Kernel 1: Polyakov -> site-major T2 ------------------------
// Coalesced LDS staging + parallel doubling scan (4 matmuls/thread via
// intra-wave __shfl). (R6 version, best measured.)
__global__ __launch_bounds__(256) void poly_kernel(const float* __restrict__ Ure,
                                                   const float* __restrict__ Uim,
                                                   u32* __restrict__ T2) {
    __shared__ float2 sm[16 * 145];   // 18.56 KB

    int line0 = blockIdx.x * 16;
    int mu    = line0 / NLINE_PER_DIR;
    int lidx0 = line0 - mu * NLINE_PER_DIR;
    int sh    = 12 - 4 * mu;
    int low0  = lidx0 & ((1 << sh) - 1);
    int high0 = lidx0 >> sh;
    int s_base0 = (high0 << (sh + 4)) | low0;

    for (int n = threadIdx.x; n < 16 * 16 * 9; n += 256) {
        int siteIdx = n / 9;
        int e       = n - siteIdx * 9;
        int site, l, c;
        if (mu == 3) { site = (lidx0 << 4) + siteIdx; l = siteIdx >> 4; c = siteIdx & 15; }
        else         { site = s_base0 + ((siteIdx >> 4) << sh) + (siteIdx & 15);
                       l = siteIdx & 15; c = siteIdx >> 4; }
        long g = ((long)site * 4 + mu) * 9 + e;
        sm[l * 145 + c * 9 + e] = make_float2(Ure[g], Uim[g]);
    }
    __syncthreads();

    int lane = threadIdx.x & 63;
    int c    = threadIdx.x & 15;
    int l    = threadIdx.x >> 4;

    M3 P;
    {
        const float2* m0 = &sm[l * 145 + c * 9];
#pragma unroll
        for (int e = 0; e < 9; e++) { float2 v = m0[e]; P.re[e] = v.x; P.im[e] = v.y; }
    }

    // doubling scan: M2(c)=U_c*U_{c+1}; M4=M2*M2(+2); M8; M16 = P_c (mod 16).
#pragma unroll
    for (int k = 1; k < 16; k <<= 1) {
        int src = (lane & 48) | ((c + k) & 15);
        M3 Q, T;
#pragma unroll
        for (int e = 0; e < 9; e++) {
            Q.re[e] = __shfl(P.re[e], src);
            Q.im[e] = __shfl(P.im[e], src);
        }
        mulM(T, P, Q);
        P = T;
    }

    int lidx = lidx0 + l;
    int low  = lidx & ((1 << sh) - 1);
    int high = lidx >> sh;
    int site = (high << (sh + 4)) | (c << sh) | low;
    u32* Tp = T2 + ((long)site * 4 + mu) * 9;
#pragma unroll
    for (int e = 0; e < 9; e++) Tp[e] = packbf(P.re[e], P.im[e]);
}

// ------- Kernel 2: plaquettes + merge-poly -> W planes -----------------------
// Direct-load version (R6 structure -- measured ~14us faster than staged R7)
// with vectorized matrix loads: 36B row = dwordx4+dwordx4+dword (24 load
// instrs/thread vs 72 scalar). Intra-block link reuse is L1-served. LDS = sw
// only (13.8 KB). One barrier total.
__global__ __launch_bounds__(192) void plaq_merge_kernel(const float* __restrict__ Ure,
                                                         const float* __restrict__ Uim,
                                                         const u32* __restrict__ T2,
                                                         u32* __restrict__ W) {
    __shared__ u32 sw[32 * WSTRIDE];     // 13,824 B

    int s0 = blockIdx.x * 32;

    // early T2 prefetch: coalesced s0*36 + it
    u32 tpre[6]; int tofs[6];
#pragma unroll
    for (int w = 0; w < 6; w++) {
        int it = threadIdx.x + w * 192;
        tpre[w] = T2[(long)s0 * 36 + it];
        int ls2 = it / 36;
        int r   = it - ls2 * 36;
        int mu2 = r / 9;
        int e2  = r - mu2 * 9;
        tofs[w] = ls2 * WSTRIDE + e2 * 12 + 6 + mu2;
    }

    int p  = threadIdx.x >> 5;
    int ls = threadIdx.x & 31;
    int s  = s0 + ls;

    int mu = (p < 3) ? 0 : ((p < 5) ? 1 : 2);
    int nu = (mu == 0) ? (p + 1) : ((mu == 1) ? (p - 1) : 3);

    M3 Umu, Unu, Unu_f, Umu_f, T1, T2m, P;
#define LDG(m, site, link) { \
        long base_ = ((long)(site) * 4 + (link)) * 9; \
        load9((m).re, Ure + base_); \
        load9((m).im, Uim + base_); }

    LDG(Umu,   s,                      mu);
    LDG(Unu,   s,                      nu);
    LDG(Unu_f, shift_site(s, mu, 1),   nu);
    LDG(Umu_f, shift_site(s, nu, 1),   mu);
#undef LDG

    mulM(T1, Umu, Unu_f);
    mulAdjM(T2m, T1, Umu_f);
    mulAdjM(P, T2m, Unu);

#pragma unroll
    for (int e = 0; e < 9; e++) sw[ls * WSTRIDE + e * 12 + p] = packbf(P.re[e], P.im[e]);

    // pad j-slots 10,11 zeroed
    for (int it = threadIdx.x; it < 32 * 9 * 2; it += 192) {
        int site = it / 18;
        int r    = it - site * 18;
        sw[site * WSTRIDE + (r >> 1) * 12 + 10 + (r & 1)] = 0u;
    }

    // T2 merge (j-slots 6..9)
#pragma unroll
    for (int w = 0; w < 6; w++) sw[tofs[w]] = tpre[w];
    __syncthreads();

    // plane-transposed write: 27 planes x 32 consecutive uint4
    uint4* W4 = (uint4*)W;
    for (int it = threadIdx.x; it < 27 * 32; it += 192) {
        int pl  = it >> 5;
        int ls2 = it & 31;
        int e   = pl / 3, q = pl - e * 3;
        const uint4 v = *(const uint4*)(sw + ls2 * WSTRIDE + e * 12 + q * 4);
        W4[(long)pl * NSITE + s0 + ls2] = v;
    }
}

// ---------------- Kernel 3: MFMA gauge-equivariant conv ----------------------
// R6 structure (direct global A loads -- LDS staging of A measured SLOWER in
// R7: barrier+LDS round-trip cost > L1-served loads) with vectorized A loads
// (48 load instrs/thread vs 144 scalar) and vectorized MODE-2 output copy.
// One wave per 16-site t-line; mfma_f32_16x16x32_bf16 per (mu,kk,e).
// LDS: somB 12.3 KB, unioned with sout 18.4 KB -> 18.4 KB.
// NOTE: never cap VGPRs via launch_bounds min-waves (round 1: 17x slower).
template <int MODE>
__global__ __launch_bounds__(256) void conv_kernel(const float* __restrict__ Ure,
                                                   const float* __restrict__ Uim,
                                                   const u32* __restrict__ W,
                                                   const float* __restrict__ omre,
                                                   const float* __restrict__ omim,
                                                   float* __restrict__ out) {
    __shared__ __align__(16) char smraw[64 * 72 * sizeof(float)];   // 18,432 B
    uint4* somB = (uint4*)smraw;   // [mk*64+lane], 12,288 B, live during loop
    float* sout = (float*)smraw;   // 18,432 B, live after loop (MODE 2)

    // B-fragment precompute: lane (c=lane&15, q=lane>>4); word w -> j=q*4+w
    for (int n = threadIdx.x; n < 12 * 64; n += 256) {
        int mk = n >> 6, ln = n & 63;
        int q = ln >> 4, c = ln & 15, i = c & 7;
        int mu = mk / 3, kk = mk - mu * 3;
        u32 wv[4];
#pragma unroll
        for (int w = 0; w < 4; w++) {
            int j = q * 4 + w;
            u32 val = 0u;
            if (q < 3 && j < NIN) {
                int oidx = ((i * NIN + j) * ND + mu) * 3 + kk;
                float orv = omre[oidx], oiv = omim[oidx];
                val = (c < 8) ? packbf(orv, -oiv) : packbf(oiv, orv);
            }
            wv[w] = val;
        }
        somB[n] = make_uint4(wv[0], wv[1], wv[2], wv[3]);
    }
    __syncthreads();

    // XCD-aware bijective swizzle (gridDim.x = 2048, divisible by 8)
    int chunk = gridDim.x >> 3;
    int lb    = ((int)blockIdx.x & 7) * chunk + ((int)blockIdx.x >> 3);

    int lane = threadIdx.x & 63;
    int wv_  = threadIdx.x >> 6;          // 0..3
    int r    = lane & 15;                 // A-row (t) / D-col (channel-part)
    int q    = lane >> 4;                 // k-quad / D-row block
    int s0b  = lb * 64;
    int sline = s0b + wv_ * 16;

    const uint4* W4 = (const uint4*)W;

    bool hi = (r >= 8);
    int  i  = r & 7;                      // output channel for epilogue
    int  reg0 = hi ? 2 : 0;               // D-rows handled by this lane

    float accr[2][9], acci[2][9];
#pragma unroll
    for (int rr = 0; rr < 2; rr++)
#pragma unroll
        for (int e = 0; e < 9; e++) { accr[rr][e] = 0.f; acci[rr][e] = 0.f; }

    for (int mu = 0; mu < ND; mu++) {
        f32x4 acc[9];
#pragma unroll
        for (int e = 0; e < 9; e++) acc[e] = (f32x4)(0.f);

        for (int kk = 0; kk < 3; kk++) {
            int mk = mu * 3 + kk;
            s16x8 bfrag = as_s16x8(somB[mk * 64 + lane]);

            int nb;
            if (mu < 3) nb = shift_site(sline, mu, kk - 1) + r;
            else        nb = sline + ((r + kk - 1) & 15);

            uint4 w9[9];
            if (q < 3) {
#pragma unroll
                for (int e = 0; e < 9; e++) w9[e] = W4[(long)(e * 3 + q) * NSITE + nb];
            } else {
#pragma unroll
                for (int e = 0; e < 9; e++) w9[e] = make_uint4(0u, 0u, 0u, 0u);
            }
#pragma unroll
            for (int e = 0; e < 9; e++)
                acc[e] = __builtin_amdgcn_mfma_f32_16x16x32_bf16(as_s16x8(w9[e]), bfrag, acc[e], 0, 0, 0);
        }

        // exchange: partner holds the other complex part of M for my 2 rows
        float own[2][9], oth[2][9];
#pragma unroll
        for (int e = 0; e < 9; e++) {
            float t0 = __shfl_xor(acc[e][0], 8);
            float t1 = __shfl_xor(acc[e][1], 8);
            float t2 = __shfl_xor(acc[e][2], 8);
            float t3 = __shfl_xor(acc[e][3], 8);
            own[0][e] = hi ? acc[e][2] : acc[e][0];
            own[1][e] = hi ? acc[e][3] : acc[e][1];
            oth[0][e] = hi ? t2 : t0;
            oth[1][e] = hi ? t3 : t1;
        }

        // sandwich A * M * A^H for this lane's 2 sites
#pragma unroll
        for (int rr = 0; rr < 2; rr++) {
            int site = sline + q * 4 + reg0 + rr;
            M3 A, M;
            {
                long base_ = ((long)site * 4 + mu) * 9;
                load9(A.re, Ure + base_);
                load9(A.im, Uim + base_);
            }
#pragma unroll
            for (int e = 0; e < 9; e++) {
                M.re[e] = hi ? oth[rr][e] : own[rr][e];
                M.im[e] = hi ? own[rr][e] : oth[rr][e];
            }
            M3 Tm;
#pragma unroll
            for (int rw = 0; rw < 3; rw++) {
#pragma unroll
                for (int cl = 0; cl < 3; cl++) {
                    float xr = 0.f, xi = 0.f;
#pragma unroll
                    for (int k = 0; k < 3; k++) {
                        float ar = A.re[rw*3+k], ai = A.im[rw*3+k];
                        float br = M.re[k*3+cl], bi = M.im[k*3+cl];
                        xr = fmaf(ar, br, xr); xr = fmaf(-ai, bi, xr);
                        xi = fmaf(ar, bi, xi); xi = fmaf(ai, br, xi);
                    }
                    Tm.re[rw*3+cl] = xr; Tm.im[rw*3+cl] = xi;
                }
            }
#pragma unroll
            for (int rw = 0; rw < 3; rw++) {
#pragma unroll
                for (int cl = 0; cl < 3; cl++) {
                    float xr = 0.f, xi = 0.f;
#pragma unroll
                    for (int k = 0; k < 3; k++) {
                        float ar = Tm.re[rw*3+k], ai = Tm.im[rw*3+k];
                        float br = A.re[cl*3+k], bi = A.im[cl*3+k];
                        xr = fmaf(ar, br, xr); xr = fmaf(ai, bi, xr);
                        if (MODE != 2) { xi = fmaf(ai, br, xi); xi = fmaf(-ar, bi, xi); }
                    }
                    accr[rr][rw*3+cl] += xr;
                    if (MODE != 2) acci[rr][rw*3+cl] += xi;
                }
            }
        }
    }

    if (MODE == 2) {
        __syncthreads();   // all somB reads done before aliasing as sout
#pragma unroll
        for (int rr = 0; rr < 2; rr++) {
            int tloc = wv_ * 16 + q * 4 + reg0 + rr;
#pragma unroll
            for (int e = 0; e < 9; e++)
                sout[(tloc * 8 + i) * 9 + e] = accr[rr][e];
        }
        __syncthreads();
        // vectorized copy: 4608 floats = 1152 float4 (both sides 16B aligned)
        float4*       o4 = (float4*)(out + (long)lb * 4608);
        const float4* s4 = (const float4*)sout;
        for (int n = threadIdx.x; n < 1152; n += 256) o4[n] = s4[n];
    } else if (MODE == 0) {
#pragma unroll
        for (int rr = 0; rr < 2; rr++) {
            int site = sline + q * 4 + reg0 + rr;
            long cb = ((long)site * 8 + i) * 9;
            float2* op = (float2*)(out + cb * 2);
#pragma unroll
            for (int e = 0; e < 9; e++) op[e] = make_float2(accr[rr][e], acci[rr][e]);
        }
    } else {
#pragma unroll
        for (int rr = 0; rr < 2; rr++) {
            int site = sline + q * 4 + reg0 + rr;
            long cb = ((long)site * 8 + i) * 9;
#pragma unroll
            for (int e = 0; e < 9; e++) {
                out[cb + e]         = accr[rr][e];
                out[NCPLX + cb + e] = acci[rr][e];
            }
        }
    }
}

extern "C" void kernel_launch(void* const* d_in, const int* in_sizes, int n_in,
                              void* d_out, int out_size, void* d_ws, size_t ws_size,
                              hipStream_t stream) {
    const float* Ure  = (const float*)d_in[0];
    const float* Uim  = (const float*)d_in[1];
    const float* omre = (const float*)d_in[2];
    const float* omim = (const float*)d_in[3];
    float* out = (float*)d_out;

    const size_t wBytes = (size_t)NSITE * WSTRIDE * sizeof(u32);   // 56.6 MB (27 planes)
    if (ws_size < wBytes) return;

    u32* W  = (u32*)d_ws;
    u32* T2 = (u32*)d_out;   // 18.9 MB temp in d_out; overwritten by conv

    poly_kernel<<<NSITE * 4 / (16 * 16), 256, 0, stream>>>(Ure, Uim, T2);
    plaq_merge_kernel<<<NSITE / 32, 192, 0, stream>>>(Ure, Uim, T2, W);

    const int convGrid = NSITE / 64;   // 2048 blocks, 64 sites each (4 waves)
    if (out_size == (int)NCPLX)
        conv_kernel<2><<<convGrid, 256, 0, stream>>>(Ure, Uim, W, omre, omim, out);
    else if (out_size == (int)(2 * NCPLX))
        conv_kernel<1><<<convGrid, 256, 0, stream>>>(Ure, Uim, W, omre, omim, out);
    else
        conv_kernel<0><<<convGrid, 256, 0, stream>>>(Ure, Uim, W, omre, omim, out);
}

// Round 9
// 208.268 us; speedup vs baseline: 1.1511x; 1.0502x over previous
//
#include <hip/hip_runtime.h>

#define LSZ   16
#define NBATCH 2
#define NSITE (NBATCH*LSZ*LSZ*LSZ*LSZ)   // 131072
#define NIN   10
#define NOUT  8
#define ND    4
#define NCPLX ((long)NSITE * NOUT * 9)   // 9,437,184 complex output elements
#define NLINE_PER_DIR (NSITE / LSZ)      // 8192
#define NLINK (NSITE * ND)               // 524288
#define WSTRIDE 108                      // u32 per site in LDS image: 9 e * 12 ch (10 used)

typedef unsigned int u32;
typedef float  f32x4 __attribute__((ext_vector_type(4)));
typedef short  s16x8 __attribute__((ext_vector_type(8)));
// dword-aligned float4 (conv epilogue loads; base only dword-aligned)
typedef float  f32x4a __attribute__((ext_vector_type(4), aligned(4)));

struct M3 { float re[9]; float im[9]; };

// load a 9-float (36B) row with 2x dwordx4 + 1 dword
__device__ __forceinline__ void load9(float d[9], const float* __restrict__ p) {
    f32x4a a = *reinterpret_cast<const f32x4a*>(p);
    f32x4a b = *reinterpret_cast<const f32x4a*>(p + 4);
    d[0] = a[0]; d[1] = a[1]; d[2] = a[2]; d[3] = a[3];
    d[4] = b[0]; d[5] = b[1]; d[6] = b[2]; d[7] = b[3];
    d[8] = p[8];
}

// bf16 pack helpers: u32 = bf16(lo) | bf16(hi)<<16
__device__ __forceinline__ unsigned short f2bf(float x) {
    u32 u = __float_as_uint(x);
    u32 r = (u + 0x7fffu + ((u >> 16) & 1u)) >> 16;   // RNE
    return (unsigned short)r;
}
__device__ __forceinline__ u32 packbf(float lo, float hi) {
    return (u32)f2bf(lo) | ((u32)f2bf(hi) << 16);
}

__device__ __forceinline__ s16x8 as_s16x8(uint4 v) {
    union { uint4 u; s16x8 s; } x; x.u = v; return x.s;
}

// o = a * b
__device__ __forceinline__ void mulM(M3& o, const M3& a, const M3& b) {
#pragma unroll
    for (int r = 0; r < 3; r++) {
#pragma unroll
        for (int c = 0; c < 3; c++) {
            float xr = 0.f, xi = 0.f;
#pragma unroll
            for (int k = 0; k < 3; k++) {
                float ar = a.re[r*3+k], ai = a.im[r*3+k];
                float br = b.re[k*3+c], bi = b.im[k*3+c];
                xr = fmaf(ar, br, xr); xr = fmaf(-ai, bi, xr);
                xi = fmaf(ar, bi, xi); xi = fmaf(ai, br, xi);
            }
            o.re[r*3+c] = xr; o.im[r*3+c] = xi;
        }
    }
}

// o = a * b^H
__device__ __forceinline__ void mulAdjM(M3& o, const M3& a, const M3& b) {
#pragma unroll
    for (int r = 0; r < 3; r++) {
#pragma unroll
        for (int c = 0; c < 3; c++) {
            float xr = 0.f, xi = 0.f;
#pragma unroll
            for (int k = 0; k < 3; k++) {
                float ar = a.re[r*3+k], ai = a.im[r*3+k];
                float br = b.re[c*3+k], bi = b.im[c*3+k];
                xr = fmaf(ar, br, xr); xr = fmaf(ai, bi, xr);
                xi = fmaf(ai, br, xi); xi = fmaf(-ar, bi, xi);
            }
            o.re[r*3+c] = xr; o.im[r*3+c] = xi;
        }
    }
}

// site s = b*65536 + x*4096 + y*256 + z*16 + t ; mu: 0->x,1->y,2->z,3->t
__device__ __forceinline__ int shift_site(int s, int mu, int k) {
    int sh = 12 - 4 * mu;
    int c  = (s >> sh) & 15;
    int nc = (c + k) & 15;
    return (s & ~(15 << sh)) | (nc << sh);
}

// ---------------- Kernel 1: Polyakov -> T2, plus plane-major Uplane ----------
// Coalesced LDS staging + parallel doubling scan. NEW (R9): each block also
// emits its 256 staged links in plane-major layout Uplane[(mu*9+e)][site]
// (float2). Across the grid every (site,mu) is staged exactly once, so this
// is a free ride on the existing read; writes are coalesced 16-site runs,
// fire-and-forget. Uplane kills the 144B-lane-stride gather pathology in
// plaq (64 L1 lines/instr -> ~8).
__global__ __launch_bounds__(256) void poly_kernel(const float* __restrict__ Ure,
                                                   const float* __restrict__ Uim,
                                                   u32* __restrict__ T2,
                                                   float2* __restrict__ Uplane) {
    __shared__ float2 sm[16 * 145];   // 18.56 KB

    int line0 = blockIdx.x * 16;
    int mu    = line0 / NLINE_PER_DIR;
    int lidx0 = line0 - mu * NLINE_PER_DIR;
    int sh    = 12 - 4 * mu;
    int low0  = lidx0 & ((1 << sh) - 1);
    int high0 = lidx0 >> sh;
    int s_base0 = (high0 << (sh + 4)) | low0;

    for (int n = threadIdx.x; n < 16 * 16 * 9; n += 256) {
        int siteIdx = n / 9;
        int e       = n - siteIdx * 9;
        int site, l, c;
        if (mu == 3) { site = (lidx0 << 4) + siteIdx; l = siteIdx >> 4; c = siteIdx & 15; }
        else         { site = s_base0 + ((siteIdx >> 4) << sh) + (siteIdx & 15);
                       l = siteIdx & 15; c = siteIdx >> 4; }
        long g = ((long)site * 4 + mu) * 9 + e;
        sm[l * 145 + c * 9 + e] = make_float2(Ure[g], Uim[g]);
    }
    __syncthreads();

    // plane-major emit: e = n>>8 (exactly 9*256 elements), idx -> (l,c,site)
    // arranged so consecutive idx -> consecutive sites (coalesced stores).
    for (int n = threadIdx.x; n < 9 * 256; n += 256) {
        int e   = n >> 8;
        int idx = n & 255;
        int l, c, site;
        if (mu == 3) { site = (lidx0 << 4) + idx; l = idx >> 4; c = idx & 15; }
        else {
            c = idx >> 4; l = idx & 15;
            int lidx = lidx0 + l;
            int low  = lidx & ((1 << sh) - 1);
            int high = lidx >> sh;
            site = (high << (sh + 4)) | (c << sh) | low;
        }
        Uplane[(long)(mu * 9 + e) * NSITE + site] = sm[l * 145 + c * 9 + e];
    }

    int lane = threadIdx.x & 63;
    int c    = threadIdx.x & 15;
    int l    = threadIdx.x >> 4;

    M3 P;
    {
        const float2* m0 = &sm[l * 145 + c * 9];
#pragma unroll
        for (int e = 0; e < 9; e++) { float2 v = m0[e]; P.re[e] = v.x; P.im[e] = v.y; }
    }

    // doubling scan: M2(c)=U_c*U_{c+1}; M4=M2*M2(+2); M8; M16 = P_c (mod 16).
#pragma unroll
    for (int k = 1; k < 16; k <<= 1) {
        int src = (lane & 48) | ((c + k) & 15);
        M3 Q, T;
#pragma unroll
        for (int e = 0; e < 9; e++) {
            Q.re[e] = __shfl(P.re[e], src);
            Q.im[e] = __shfl(P.im[e], src);
        }
        mulM(T, P, Q);
        P = T;
    }

    int lidx = lidx0 + l;
    int low  = lidx & ((1 << sh) - 1);
    int high = lidx >> sh;
    int site = (high << (sh + 4)) | (c << sh) | low;
    u32* Tp = T2 + ((long)site * 4 + mu) * 9;
#pragma unroll
    for (int e = 0; e < 9; e++) Tp[e] = packbf(P.re[e], P.im[e]);
}

// ------- Kernel 2: plaquettes + merge-poly -> W planes -----------------------
// R6 direct-load structure (threads/LDS/barriers identical) but matrices read
// from plane-major Uplane: lane stride 8B (32 consecutive sites) instead of
// 144B -> ~8 L1 lines per load instr instead of ~64. Pure address-pattern
// change = clean test of the TA/line-throughput theory.
__global__ __launch_bounds__(192) void plaq_merge_kernel(const float2* __restrict__ Uplane,
                                                         const u32* __restrict__ T2,
                                                         u32* __restrict__ W) {
    __shared__ u32 sw[32 * WSTRIDE];     // 13,824 B

    int s0 = blockIdx.x * 32;

    // early T2 prefetch: coalesced s0*36 + it
    u32 tpre[6]; int tofs[6];
#pragma unroll
    for (int w = 0; w < 6; w++) {
        int it = threadIdx.x + w * 192;
        tpre[w] = T2[(long)s0 * 36 + it];
        int ls2 = it / 36;
        int r   = it - ls2 * 36;
        int mu2 = r / 9;
        int e2  = r - mu2 * 9;
        tofs[w] = ls2 * WSTRIDE + e2 * 12 + 6 + mu2;
    }

    int p  = threadIdx.x >> 5;
    int ls = threadIdx.x & 31;
    int s  = s0 + ls;

    int mu = (p < 3) ? 0 : ((p < 5) ? 1 : 2);
    int nu = (mu == 0) ? (p + 1) : ((mu == 1) ? (p - 1) : 3);

    M3 Umu, Unu, Unu_f, Umu_f, T1, T2m, P;
#define LDP(m, site_, link_) { \
        const float2* pp = Uplane + (long)(link_) * 9 * NSITE + (site_); \
        _Pragma("unroll") \
        for (int e = 0; e < 9; e++) { float2 v = pp[(long)e * NSITE]; (m).re[e] = v.x; (m).im[e] = v.y; } }

    LDP(Umu,   s,                      mu);
    LDP(Unu,   s,                      nu);
    LDP(Unu_f, shift_site(s, mu, 1),   nu);
    LDP(Umu_f, shift_site(s, nu, 1),   mu);
#undef LDP

    mulM(T1, Umu, Unu_f);
    mulAdjM(T2m, T1, Umu_f);
    mulAdjM(P, T2m, Unu);

#pragma unroll
    for (int e = 0; e < 9; e++) sw[ls * WSTRIDE + e * 12 + p] = packbf(P.re[e], P.im[e]);

    // pad j-slots 10,11 zeroed
    for (int it = threadIdx.x; it < 32 * 9 * 2; it += 192) {
        int site = it / 18;
        int r    = it - site * 18;
        sw[site * WSTRIDE + (r >> 1) * 12 + 10 + (r & 1)] = 0u;
    }

    // T2 merge (j-slots 6..9)
#pragma unroll
    for (int w = 0; w < 6; w++) sw[tofs[w]] = tpre[w];
    __syncthreads();

    // plane-transposed write: 27 planes x 32 consecutive uint4
    uint4* W4 = (uint4*)W;
    for (int it = threadIdx.x; it < 27 * 32; it += 192) {
        int pl  = it >> 5;
        int ls2 = it & 31;
        int e   = pl / 3, q = pl - e * 3;
        const uint4 v = *(const uint4*)(sw + ls2 * WSTRIDE + e * 12 + q * 4);
        W4[(long)pl * NSITE + s0 + ls2] = v;
    }
}

// ---------------- Kernel 3: MFMA gauge-equivariant conv ----------------------
// UNCHANGED from R8 (control). One wave per 16-site t-line;
// mfma_f32_16x16x32_bf16 per (mu,kk,e); f32 sandwich epilogue.
// NOTE: never cap VGPRs via launch_bounds min-waves (round 1: 17x slower).
template <int MODE>
__global__ __launch_bounds__(256) void conv_kernel(const float* __restrict__ Ure,
                                                   const float* __restrict__ Uim,
                                                   const u32* __restrict__ W,
                                                   const float* __restrict__ omre,
                                                   const float* __restrict__ omim,
                                                   float* __restrict__ out) {
    __shared__ __align__(16) char smraw[64 * 72 * sizeof(float)];   // 18,432 B
    uint4* somB = (uint4*)smraw;   // [mk*64+lane], 12,288 B, live during loop
    float* sout = (float*)smraw;   // 18,432 B, live after loop (MODE 2)

    // B-fragment precompute: lane (c=lane&15, q=lane>>4); word w -> j=q*4+w
    for (int n = threadIdx.x; n < 12 * 64; n += 256) {
        int mk = n >> 6, ln = n & 63;
        int q = ln >> 4, c = ln & 15, i = c & 7;
        int mu = mk / 3, kk = mk - mu * 3;
        u32 wv[4];
#pragma unroll
        for (int w = 0; w < 4; w++) {
            int j = q * 4 + w;
            u32 val = 0u;
            if (q < 3 && j < NIN) {
                int oidx = ((i * NIN + j) * ND + mu) * 3 + kk;
                float orv = omre[oidx], oiv = omim[oidx];
                val = (c < 8) ? packbf(orv, -oiv) : packbf(oiv, orv);
            }
            wv[w] = val;
        }
        somB[n] = make_uint4(wv[0], wv[1], wv[2], wv[3]);
    }
    __syncthreads();

    // XCD-aware bijective swizzle (gridDim.x = 2048, divisible by 8)
    int chunk = gridDim.x >> 3;
    int lb    = ((int)blockIdx.x & 7) * chunk + ((int)blockIdx.x >> 3);

    int lane = threadIdx.x & 63;
    int wv_  = threadIdx.x >> 6;          // 0..3
    int r    = lane & 15;                 // A-row (t) / D-col (channel-part)
    int q    = lane >> 4;                 // k-quad / D-row block
    int s0b  = lb * 64;
    int sline = s0b + wv_ * 16;

    const uint4* W4 = (const uint4*)W;

    bool hi = (r >= 8);
    int  i  = r & 7;                      // output channel for epilogue
    int  reg0 = hi ? 2 : 0;               // D-rows handled by this lane

    float accr[2][9], acci[2][9];
#pragma unroll
    for (int rr = 0; rr < 2; rr++)
#pragma unroll
        for (int e = 0; e < 9; e++) { accr[rr][e] = 0.f; acci[rr][e] = 0.f; }

    for (int mu = 0; mu < ND; mu++) {
        f32x4 acc[9];
#pragma unroll
        for (int e = 0; e < 9; e++) acc[e] = (f32x4)(0.f);

        for (int kk = 0; kk < 3; kk++) {
            int mk = mu * 3 + kk;
            s16x8 bfrag = as_s16x8(somB[mk * 64 + lane]);

            int nb;
            if (mu < 3) nb = shift_site(sline, mu, kk - 1) + r;
            else        nb = sline + ((r + kk - 1) & 15);

            uint4 w9[9];
            if (q < 3) {
#pragma unroll
                for (int e = 0; e < 9; e++) w9[e] = W4[(long)(e * 3 + q) * NSITE + nb];
            } else {
#pragma unroll
                for (int e = 0; e < 9; e++) w9[e] = make_uint4(0u, 0u, 0u, 0u);
            }
#pragma unroll
            for (int e = 0; e < 9; e++)
                acc[e] = __builtin_amdgcn_mfma_f32_16x16x32_bf16(as_s16x8(w9[e]), bfrag, acc[e], 0, 0, 0);
        }

        // exchange: partner holds the other complex part of M for my 2 rows
        float own[2][9], oth[2][9];
#pragma unroll
        for (int e = 0; e < 9; e++) {
            float t0 = __shfl_xor(acc[e][0], 8);
            float t1 = __shfl_xor(acc[e][1], 8);
            float t2 = __shfl_xor(acc[e][2], 8);
            float t3 = __shfl_xor(acc[e][3], 8);
            own[0][e] = hi ? acc[e][2] : acc[e][0];
            own[1][e] = hi ? acc[e][3] : acc[e][1];
            oth[0][e] = hi ? t2 : t0;
            oth[1][e] = hi ? t3 : t1;
        }

        // sandwich A * M * A^H for this lane's 2 sites
#pragma unroll
        for (int rr = 0; rr < 2; rr++) {
            int site = sline + q * 4 + reg0 + rr;
            M3 A, M;
            {
                long base_ = ((long)site * 4 + mu) * 9;
                load9(A.re, Ure + base_);
                load9(A.im, Uim + base_);
            }
#pragma unroll
            for (int e = 0; e < 9; e++) {
                M.re[e] = hi ? oth[rr][e] : own[rr][e];
                M.im[e] = hi ? own[rr][e] : oth[rr][e];
            }
            M3 Tm;
#pragma unroll
            for (int rw = 0; rw < 3; rw++) {
#pragma unroll
                for (int cl = 0; cl < 3; cl++) {
                    float xr = 0.f, xi = 0.f;
#pragma unroll
                    for (int k = 0; k < 3; k++) {
                        float ar = A.re[rw*3+k], ai = A.im[rw*3+k];
                        float br = M.re[k*3+cl], bi = M.im[k*3+cl];
                        xr = fmaf(ar, br, xr); xr = fmaf(-ai, bi, xr);
                        xi = fmaf(ar, bi, xi); xi = fmaf(ai, br, xi);
                    }
                    Tm.re[rw*3+cl] = xr; Tm.im[rw*3+cl] = xi;
                }
            }
#pragma unroll
            for (int rw = 0; rw < 3; rw++) {
#pragma unroll
                for (int cl = 0; cl < 3; cl++) {
                    float xr = 0.f, xi = 0.f;
#pragma unroll
                    for (int k = 0; k < 3; k++) {
                        float ar = Tm.re[rw*3+k], ai = Tm.im[rw*3+k];
                        float br = A.re[cl*3+k], bi = A.im[cl*3+k];
                        xr = fmaf(ar, br, xr); xr = fmaf(ai, bi, xr);
                        if (MODE != 2) { xi = fmaf(ai, br, xi); xi = fmaf(-ar, bi, xi); }
                    }
                    accr[rr][rw*3+cl] += xr;
                    if (MODE != 2) acci[rr][rw*3+cl] += xi;
                }
            }
        }
    }

    if (MODE == 2) {
        __syncthreads();   // all somB reads done before aliasing as sout
#pragma unroll
        for (int rr = 0; rr < 2; rr++) {
            int tloc = wv_ * 16 + q * 4 + reg0 + rr;
#pragma unroll
            for (int e = 0; e < 9; e++)
                sout[(tloc * 8 + i) * 9 + e] = accr[rr][e];
        }
        __syncthreads();
        // vectorized copy: 4608 floats = 1152 float4
        float4*       o4 = (float4*)(out + (long)lb * 4608);
        const float4* s4 = (const float4*)sout;
        for (int n = threadIdx.x; n < 1152; n += 256) o4[n] = s4[n];
    } else if (MODE == 0) {
#pragma unroll
        for (int rr = 0; rr < 2; rr++) {
            int site = sline + q * 4 + reg0 + rr;
            long cb = ((long)site * 8 + i) * 9;
            float2* op = (float2*)(out + cb * 2);
#pragma unroll
            for (int e = 0; e < 9; e++) op[e] = make_float2(accr[rr][e], acci[rr][e]);
        }
    } else {
#pragma unroll
        for (int rr = 0; rr < 2; rr++) {
            int site = sline + q * 4 + reg0 + rr;
            long cb = ((long)site * 8 + i) * 9;
#pragma unroll
            for (int e = 0; e < 9; e++) {
                out[cb + e]         = accr[rr][e];
                out[NCPLX + cb + e] = acci[rr][e];
            }
        }
    }
}

extern "C" void kernel_launch(void* const* d_in, const int* in_sizes, int n_in,
                              void* d_out, int out_size, void* d_ws, size_t ws_size,
                              hipStream_t stream) {
    const float* Ure  = (const float*)d_in[0];
    const float* Uim  = (const float*)d_in[1];
    const float* omre = (const float*)d_in[2];
    const float* omim = (const float*)d_in[3];
    float* out = (float*)d_out;

    const size_t wBytes  = (size_t)NSITE * WSTRIDE * sizeof(u32);     // 56.6 MB (27 planes)
    const size_t upBytes = (size_t)36 * NSITE * sizeof(float2);       // 37.7 MB plane-major U
    if (ws_size < wBytes + upBytes) return;

    u32*    W      = (u32*)d_ws;
    float2* Uplane = (float2*)((char*)d_ws + wBytes);
    u32*    T2     = (u32*)d_out;   // 18.9 MB temp in d_out; overwritten by conv

    poly_kernel<<<NSITE * 4 / (16 * 16), 256, 0, stream>>>(Ure, Uim, T2, Uplane);
    plaq_merge_kernel<<<NSITE / 32, 192, 0, stream>>>(Uplane, T2, W);

    const int convGrid = NSITE / 64;   // 2048 blocks, 64 sites each (4 waves)
    if (out_size == (int)NCPLX)
        conv_kernel<2><<<convGrid, 256, 0, stream>>>(Ure, Uim, W, omre, omim, out);
    else if (out_size == (int)(2 * NCPLX))
        conv_kernel<1><<<convGrid, 256, 0, stream>>>(Ure, Uim, W, omre, omim, out);
    else
        conv_kernel<0><<<convGrid, 256, 0, stream>>>(Ure, Uim, W, omre, omim, out);
}